// Round 2
// baseline (2193.554 us; speedup 1.0000x reference)
//
#include <hip/hip_runtime.h>
#include <hip/hip_fp16.h>

#define NHEAD 16
#define DHEAD 128
#define DMODEL 2048
#define SEQ 4096
#define BATCH 4
#define MROWS (BATCH*SEQ)   // 16384

typedef _Float16 f16x8 __attribute__((ext_vector_type(8)));
typedef _Float16 f16x4 __attribute__((ext_vector_type(4)));
typedef float f32x4 __attribute__((ext_vector_type(4)));

// ---------------- elementwise fp32 -> fp16 (hi, lo) split ----------------
__global__ __launch_bounds__(256) void split_f32_f16(
    const float* __restrict__ x, _Float16* __restrict__ hi,
    _Float16* __restrict__ lo, int n4) {
  int i = blockIdx.x * blockDim.x + threadIdx.x;
  int stride = gridDim.x * blockDim.x;
  for (; i < n4; i += stride) {
    float4 v = ((const float4*)x)[i];
    f16x4 h, l;
    h[0] = (_Float16)v.x; h[1] = (_Float16)v.y;
    h[2] = (_Float16)v.z; h[3] = (_Float16)v.w;
    ((f16x4*)hi)[i] = h;
    if (lo) {
      l[0] = (_Float16)(v.x - (float)h[0]);
      l[1] = (_Float16)(v.y - (float)h[1]);
      l[2] = (_Float16)(v.z - (float)h[2]);
      l[3] = (_Float16)(v.w - (float)h[3]);
      ((f16x4*)lo)[i] = l;
    }
  }
}

// ------------- weight transpose + split: W[K][N] -> WT[N][K] f16 ---------
__global__ __launch_bounds__(256) void transpose_split(
    const float* __restrict__ W, _Float16* __restrict__ hi,
    _Float16* __restrict__ lo, int rows, int cols) {
  __shared__ float tile[32][33];
  int tx = threadIdx.x, ty = threadIdx.y;          // 32 x 8
  int c = blockIdx.x * 32 + tx;
  for (int r0 = 0; r0 < 32; r0 += 8) {
    int r = blockIdx.y * 32 + ty + r0;
    tile[ty + r0][tx] = W[(size_t)r * cols + c];
  }
  __syncthreads();
  for (int r0 = 0; r0 < 32; r0 += 8) {
    int n = blockIdx.x * 32 + ty + r0;             // WT row = original col
    int k = blockIdx.y * 32 + tx;                  // WT col = original row
    float v = tile[tx][ty + r0];                   // = W[k][n]
    _Float16 h = (_Float16)v;
    hi[(size_t)n * rows + k] = h;
    if (lo) lo[(size_t)n * rows + k] = (_Float16)(v - (float)h);
  }
}

// ---- per-head column sums of W in fp64: CS[k][h] = sum_d W[k][h*128+d] ---
__global__ __launch_bounds__(256) void colsum_f64(
    const float* __restrict__ W, double* __restrict__ CS) {
  const int k = blockIdx.x;                 // row of W
  const int t = threadIdx.x;
  const int h = t >> 4, s = t & 15;
  double acc = 0.0;
  const float* p = W + (size_t)k * DMODEL + h * DHEAD + s * 8;
#pragma unroll
  for (int i = 0; i < 8; i++) acc += (double)p[i];
#pragma unroll
  for (int m = 1; m < 16; m <<= 1) acc += __shfl_xor(acc, m, 64);
  if (s == 0) CS[(size_t)k * NHEAD + h] = acc;
}

// ---- exact per-head row sums: rs[row][h] = sum_k X[row][k] * CS[k][h] ----
__global__ __launch_bounds__(256) void rowsum_f64(
    const float* __restrict__ X, const double* __restrict__ CS,
    float* __restrict__ rs) {
  __shared__ double red[16][17];
  const int row = blockIdx.x;
  const int t = threadIdx.x;
  const int h = t & 15, c = t >> 4;         // 16 k-chunks x 16 heads
  const float* xp = X + (size_t)row * DMODEL + c * 128;
  const double* cp = CS + (size_t)c * 128 * NHEAD + h;
  double acc = 0.0;
#pragma unroll 8
  for (int i = 0; i < 128; i++)
    acc += (double)xp[i] * cp[(size_t)i * NHEAD];
  red[c][h] = acc;
  __syncthreads();
  if (t < 16) {
    double s = 0.0;
#pragma unroll
    for (int c2 = 0; c2 < 16; c2++) s += red[c2][t];
    rs[(size_t)row * NHEAD + t] = (float)s;
  }
}

// ---------------- fp16(-split) MFMA GEMM: C[M,N] = A[M,K] @ BT[N,K]^T ----
__device__ inline void glds16(const void* g, void* l) {
  __builtin_amdgcn_global_load_lds(
      (const __attribute__((address_space(1))) unsigned int*)g,
      (__attribute__((address_space(3))) unsigned int*)l, 16, 0, 0);
}

template <int NPASS, int OUT_HALF>
__global__ __launch_bounds__(256) void gemm_f16(
    const _Float16* __restrict__ Ahi, const _Float16* __restrict__ Alo,
    const _Float16* __restrict__ Bhi, const _Float16* __restrict__ Blo,
    float* __restrict__ Cf, _Float16* __restrict__ Ch,
    int M, int N, int Kd) {
  __shared__ _Float16 lds[4 * 128 * 32];
  _Float16* sAh = lds;
  _Float16* sAl = lds + 4096;
  _Float16* sBh = lds + 8192;
  _Float16* sBl = lds + 12288;

  const int t = threadIdx.x;
  const int lane = t & 63, wid = t >> 6;
  const int wm = wid >> 1, wn = wid & 1;           // 2x2 waves, 64x64 each
  const int lr = lane & 15, lk = (lane >> 4) * 8;
  const int m0 = blockIdx.x * 128, n0 = blockIdx.y * 128;

  f32x4 acc[4][4] = {};

  for (int k0 = 0; k0 < Kd; k0 += 32) {
    // stage: 128x32 f16 tile, linear LDS, 2 x 16B per thread per tile
#pragma unroll
    for (int i = 0; i < 2; i++) {
      int slot = t + i * 256;
      int row = slot >> 2, kc = (slot & 3) * 8;
      glds16(Ahi + (size_t)(m0 + row) * Kd + k0 + kc, sAh + slot * 8);
      glds16(Bhi + (size_t)(n0 + row) * Kd + k0 + kc, sBh + slot * 8);
      if (NPASS == 3) {
        glds16(Alo + (size_t)(m0 + row) * Kd + k0 + kc, sAl + slot * 8);
        glds16(Blo + (size_t)(n0 + row) * Kd + k0 + kc, sBl + slot * 8);
      }
    }
    __syncthreads();

    f16x8 ah[4], bh[4], al[4], bl[4];
#pragma unroll
    for (int f = 0; f < 4; f++) {
      ah[f] = *(const f16x8*)&sAh[(wm * 64 + f * 16 + lr) * 32 + lk];
      bh[f] = *(const f16x8*)&sBh[(wn * 64 + f * 16 + lr) * 32 + lk];
      if (NPASS == 3) {
        al[f] = *(const f16x8*)&sAl[(wm * 64 + f * 16 + lr) * 32 + lk];
        bl[f] = *(const f16x8*)&sBl[(wn * 64 + f * 16 + lr) * 32 + lk];
      }
    }
#pragma unroll
    for (int i = 0; i < 4; i++)
#pragma unroll
      for (int j = 0; j < 4; j++) {
        acc[i][j] = __builtin_amdgcn_mfma_f32_16x16x32_f16(ah[i], bh[j], acc[i][j], 0, 0, 0);
        if (NPASS == 3) {
          acc[i][j] = __builtin_amdgcn_mfma_f32_16x16x32_f16(ah[i], bl[j], acc[i][j], 0, 0, 0);
          acc[i][j] = __builtin_amdgcn_mfma_f32_16x16x32_f16(al[i], bh[j], acc[i][j], 0, 0, 0);
        }
      }
    __syncthreads();
  }

  // epilogue: C[row][col], row=(lane>>4)*4+r within 16-frag, col=lane&15
#pragma unroll
  for (int i = 0; i < 4; i++) {
    int row = m0 + wm * 64 + i * 16 + (lane >> 4) * 4;
#pragma unroll
    for (int j = 0; j < 4; j++) {
      int col = n0 + wn * 64 + j * 16 + (lane & 15);
#pragma unroll
      for (int r = 0; r < 4; r++) {
        if (OUT_HALF)
          Ch[(size_t)(row + r) * N + col] = (_Float16)acc[i][j][r];
        else
          Cf[(size_t)(row + r) * N + col] = acc[i][j][r];
      }
    }
  }
}

// -------- per-position head attention: 1 block (256 thr) per (b,s) -------
__global__ __launch_bounds__(256) void attn_kernel(
    const float* __restrict__ Q, const float* __restrict__ K,
    const _Float16* __restrict__ V, const float* __restrict__ mask,
    const float* __restrict__ rsQ, const float* __restrict__ rsK,
    float* __restrict__ wout, _Float16* __restrict__ aout) {
  __shared__ float lq[16][129], lkk[16][129], lv[16][128], lw[16][16];
  const int pos = blockIdx.x;
  const int t = threadIdx.x;
  const int h = t >> 4, j = t & 15;
  const size_t base = (size_t)pos * DMODEL + h * DHEAD + j;

  // load q and k rows; normalize by the EXACT (fp64-path) row sums
  const float iq = 1.f / (rsQ[(size_t)pos * NHEAD + h] + 1e-6f);
  const float ik = 1.f / (rsK[(size_t)pos * NHEAD + h] + 1e-6f);
#pragma unroll
  for (int i = 0; i < 8; i++) lq[h][j + 16 * i] = Q[base + 16 * i] * iq;
#pragma unroll
  for (int i = 0; i < 8; i++) lkk[h][j + 16 * i] = K[base + 16 * i] * ik;
#pragma unroll
  for (int i = 0; i < 8; i++) lv[h][j + 16 * i] = (float)V[base + 16 * i];
  __syncthreads();

  // logits: thread t -> (q=h, k=j)
  float dot = 0.f;
#pragma unroll 8
  for (int d = 0; d < 128; d++) dot += lq[h][d] * lkk[j][d];
  float mk = mask[(size_t)pos * 256 + t];
  float x = (dot - 1e9f * mk) * 0.08838834764831845f;  // 1/sqrt(128)
  float mx = x;
#pragma unroll
  for (int m = 1; m < 16; m <<= 1) mx = fmaxf(mx, __shfl_xor(mx, m, 64));
  float e = expf(x - mx);
  float den = e;
#pragma unroll
  for (int m = 1; m < 16; m <<= 1) den += __shfl_xor(den, m, 64);
  float w = e / den;
  wout[(size_t)pos * 256 + t] = w;
  lw[h][j] = w;
  __syncthreads();

  // attn[q][d] = sum_k w[q][k] * v[k][d]; thread t -> q=h, d = j + 16*i
#pragma unroll
  for (int i = 0; i < 8; i++) {
    int d = j + 16 * i;
    float a = 0.f;
#pragma unroll
    for (int k2 = 0; k2 < 16; k2++) a += lw[h][k2] * lv[k2][d];
    aout[(size_t)pos * DMODEL + h * DHEAD + d] = (_Float16)a;
  }
}

// -------------------------------------------------------------------------
extern "C" void kernel_launch(void* const* d_in, const int* in_sizes, int n_in,
                              void* d_out, int out_size, void* d_ws, size_t ws_size,
                              hipStream_t stream) {
  const float* query = (const float*)d_in[0];
  const float* key   = (const float*)d_in[1];
  const float* value = (const float*)d_in[2];
  const float* mask  = (const float*)d_in[3];
  const float* Wq = (const float*)d_in[4];
  const float* Wk = (const float*)d_in[5];
  const float* Wv = (const float*)d_in[6];
  const float* Wo = (const float*)d_in[7];

  float* out  = (float*)d_out;                       // [16384, 2048] fp32
  float* wout = out + (size_t)MROWS * DMODEL;        // [16384, 256] fp32

  const size_t SZ_HALF = (size_t)MROWS * DMODEL * 2; // 67.1 MB
  const size_t SZ_F32  = (size_t)MROWS * DMODEL * 4; // 134.2 MB
  const size_t SZ_W    = (size_t)DMODEL * DMODEL * 2;// 8.4 MB
  const size_t SZ_CS   = (size_t)DMODEL * NHEAD * 8; // 256 KB
  const size_t SZ_RS   = (size_t)MROWS * NHEAD * 4;  // 1 MB
  const size_t NEED = 3 * SZ_HALF + SZ_F32 + 2 * SZ_W + 2 * SZ_CS + 2 * SZ_RS;
  if (ws_size < NEED) return;  // workspace too small — fail visibly

  char* ws = (char*)d_ws;
  _Float16* a_hi  = (_Float16*)ws;
  _Float16* a_lo  = (_Float16*)(ws + SZ_HALF);
  float*    Kbuf  = (float*)   (ws + 2 * SZ_HALF);
  _Float16* Vbuf  = (_Float16*)(ws + 2 * SZ_HALF + SZ_F32);
  _Float16* wT_hi = (_Float16*)(ws + 3 * SZ_HALF + SZ_F32);
  _Float16* wT_lo = (_Float16*)(ws + 3 * SZ_HALF + SZ_F32 + SZ_W);
  double*   CSq   = (double*)  (ws + 3 * SZ_HALF + SZ_F32 + 2 * SZ_W);
  double*   CSk   = (double*)  (ws + 3 * SZ_HALF + SZ_F32 + 2 * SZ_W + SZ_CS);
  float*    rsQ   = (float*)   (ws + 3 * SZ_HALF + SZ_F32 + 2 * SZ_W + 2 * SZ_CS);
  float*    rsK   = (float*)   (ws + 3 * SZ_HALF + SZ_F32 + 2 * SZ_W + 2 * SZ_CS + SZ_RS);
  _Float16* attn  = a_hi;        // reused after V-GEMM consumed a_hi
  float*    Qbuf  = out;         // Q fp32 parked in d_out, overwritten last

  const int n4 = MROWS * DMODEL / 4;
  dim3 ggrid(MROWS / 128, DMODEL / 128);
  dim3 tgrid(DMODEL / 32, DMODEL / 32);
  dim3 tblk(32, 8);

  // exact per-head row sums (fp64 side channel)
  colsum_f64<<<DMODEL, 256, 0, stream>>>(Wq, CSq);
  colsum_f64<<<DMODEL, 256, 0, stream>>>(Wk, CSk);
  rowsum_f64<<<MROWS, 256, 0, stream>>>(query, CSq, rsQ);
  rowsum_f64<<<MROWS, 256, 0, stream>>>(key, CSk, rsK);

  // Q path (3-pass split fp16 -> near-fp32)
  split_f32_f16<<<4096, 256, 0, stream>>>(query, a_hi, a_lo, n4);
  transpose_split<<<tgrid, tblk, 0, stream>>>(Wq, wT_hi, wT_lo, DMODEL, DMODEL);
  gemm_f16<3, 0><<<ggrid, 256, 0, stream>>>(a_hi, a_lo, wT_hi, wT_lo,
                                            Qbuf, nullptr, MROWS, DMODEL, DMODEL);
  // K path
  split_f32_f16<<<4096, 256, 0, stream>>>(key, a_hi, a_lo, n4);
  transpose_split<<<tgrid, tblk, 0, stream>>>(Wk, wT_hi, wT_lo, DMODEL, DMODEL);
  gemm_f16<3, 0><<<ggrid, 256, 0, stream>>>(a_hi, a_lo, wT_hi, wT_lo,
                                            Kbuf, nullptr, MROWS, DMODEL, DMODEL);
  // V path (1-pass fp16)
  split_f32_f16<<<4096, 256, 0, stream>>>(value, a_hi, nullptr, n4);
  transpose_split<<<tgrid, tblk, 0, stream>>>(Wv, wT_hi, nullptr, DMODEL, DMODEL);
  gemm_f16<1, 1><<<ggrid, 256, 0, stream>>>(a_hi, nullptr, wT_hi, nullptr,
                                            nullptr, Vbuf, MROWS, DMODEL, DMODEL);
  // per-position head attention
  attn_kernel<<<MROWS, 256, 0, stream>>>(Qbuf, Kbuf, Vbuf, mask, rsQ, rsK, wout, attn);
  // output GEMM (1-pass fp16)
  transpose_split<<<tgrid, tblk, 0, stream>>>(Wo, wT_hi, nullptr, DMODEL, DMODEL);
  gemm_f16<1, 0><<<ggrid, 256, 0, stream>>>(attn, nullptr, wT_hi, nullptr,
                                            out, nullptr, MROWS, DMODEL, DMODEL);
}